// Round 4
// baseline (77.216 us; speedup 1.0000x reference)
//
#include <hip/hip_runtime.h>
#include <hip/hip_bf16.h>

// Problem constants (reference: N=768, D_IN=308, H=100, iterations=1)
// Inputs f32 (npz forensics). OUTPUT F32 (reference returns float32; harness
// contract: d_out is the reference's output dtype -> float*).
#define NW   768
#define HID  100
#define DIN  308

typedef const float* fp;

// ---------------------------------------------------------------------------
// K0: probe integer-tensor storage.
// modes[0] (nf):  0 = one int32 word per element, 1 = packed uint8 bools,
//                 2 = int64 per element (read low word at 2*i)
// modes[1] (idx): 0 = int32, 1 = int64
// Reads 192 words = 768 bytes from each buffer — in-bounds for every
// candidate layout (nf >= 768 bytes, idx >= 15360 bytes).
// ---------------------------------------------------------------------------
__global__ __launch_bounds__(192) void k_probe(const int* __restrict__ nf,
                                               const int* __restrict__ idx,
                                               int* __restrict__ modes) {
    __shared__ int bigNF, badNF, oddNF, evenNF, oddIX, evenIX;
    if (threadIdx.x == 0) { bigNF = badNF = oddNF = evenNF = oddIX = evenIX = 0; }
    __syncthreads();
    const int t = threadIdx.x;
    const unsigned vn = (unsigned)nf[t];
    if (vn > 1u) atomicOr(&bigNF, 1);
    if (vn & 0xFEFEFEFEu) atomicOr(&badNF, 1);   // some byte > 1 -> not packed bools
    if ((t & 1) && vn) atomicOr(&oddNF, 1);
    if (!(t & 1) && vn) atomicOr(&evenNF, 1);
    const unsigned vi = (unsigned)idx[t];
    if ((t & 1) && vi) atomicOr(&oddIX, 1);
    if (!(t & 1) && vi) atomicOr(&evenIX, 1);
    __syncthreads();
    if (t == 0) {
        int m = 0;
        if (!badNF && bigNF) m = 1;              // multi-byte 0/1 pattern -> bytes
        else if (!oddNF && evenNF) m = 2;        // [v,0,v,0,...] -> int64
        modes[0] = m;
        modes[1] = (!oddIX && evenIX) ? 1 : 0;   // idx int64 signature
    }
}

// ---------------------------------------------------------------------------
// K1: uu = tanh(vv @ A_W + A_b)        (768x308)@(308x100) -> f32 (768x100)
// ---------------------------------------------------------------------------
__global__ __launch_bounds__(128) void k_uu(fp vv, fp A_W, fp A_b,
                                            float* __restrict__ uu) {
    __shared__ float vs[DIN];
    const int i = blockIdx.x;
    for (int t = threadIdx.x; t < DIN; t += 128) vs[t] = vv[i * DIN + t];
    __syncthreads();
    const int t = threadIdx.x;
    if (t < HID) {
        float acc = A_b[t];
#pragma unroll 4
        for (int k = 0; k < DIN; ++k)
            acc = fmaf(vs[k], A_W[k * HID + t], acc);
        uu[i * HID + t] = tanhf(acc);
    }
}

// ---------------------------------------------------------------------------
// K2 (fused, row-local after gather):
//   ww = gather 5 neighbor uu rows (zeroed if not_found); bb = tanh(ww@B_W[:500]+B_b)
//   oo = tanh(bb@B2_Wo+B2_bo); per head: hl = oo@W1[:100]+b1, hr = oo@W1[100:]
// hlhr layout: [head][0=hl/1=hr][row][100] f32
// ---------------------------------------------------------------------------
__global__ __launch_bounds__(128) void k_fused(
    const float* __restrict__ uu, const int* __restrict__ indices,
    const int* __restrict__ nf, const int* __restrict__ modes,
    fp B_W, fp B_b, fp B2_Wo, fp B2_bo,
    fp W1r, fp b1r, fp W1c, fp b1c, fp W1e, fp b1e,
    float* __restrict__ hlhr) {
    __shared__ float ww[5 * HID];
    __shared__ float bbs[HID];
    __shared__ float oos[HID];
    const int i = blockIdx.x;
    const int mnf = modes[0], midx = modes[1];
    const bool notf = (mnf == 1) ? (((const unsigned char*)nf)[i] != 0)
                    : (mnf == 2) ? (nf[2 * i] != 0)
                                 : (nf[i] != 0);
    for (int t = threadIdx.x; t < 5 * HID; t += 128) {
        const int q = t / HID, c = t % HID;
        int j = midx ? indices[2 * (i * 5 + q)] : indices[i * 5 + q];
        j = (j < 0) ? 0 : ((j >= NW) ? NW - 1 : j);  // stay finite if misparsed
        ww[t] = notf ? 0.f : uu[j * HID + c];
    }
    __syncthreads();
    const int t = threadIdx.x;
    if (t < HID) {
        float acc = B_b[t];
#pragma unroll 4
        for (int k = 0; k < 5 * HID; ++k)
            acc = fmaf(ww[k], B_W[k * HID + t], acc);
        bbs[t] = tanhf(acc);
    }
    __syncthreads();
    if (t < HID) {
        float acc = B2_bo[t];
#pragma unroll 4
        for (int k = 0; k < HID; ++k)
            acc = fmaf(bbs[k], B2_Wo[k * HID + t], acc);
        oos[t] = tanhf(acc);
    }
    __syncthreads();
    if (t < HID) {
        fp W1s[3] = {W1r, W1c, W1e};
        fp b1s[3] = {b1r, b1c, b1e};
#pragma unroll
        for (int h = 0; h < 3; ++h) {
            float accl = b1s[h][t];  // fold b1 into hl
            float accr = 0.f;
#pragma unroll 4
            for (int k = 0; k < HID; ++k) {
                const float o = oos[k];
                accl = fmaf(o, W1s[h][k * HID + t], accl);
                accr = fmaf(o, W1s[h][(HID + k) * HID + t], accr);
            }
            hlhr[(size_t)(h * 2 + 0) * (NW * HID) + i * HID + t] = accl;
            hlhr[(size_t)(h * 2 + 1) * (NW * HID) + i * HID + t] = accr;
        }
    }
}

// ---------------------------------------------------------------------------
// K3: out[h][i][j][:] = relu(hl_i + hr_j) @ W2h + b2h   (f32 output!)
// 32x32 pair tile / block (256 thr), 2x2 micro-tile / thread, swizzled LDS.
// ---------------------------------------------------------------------------
__device__ __forceinline__ int swzi(int r, int c) {
    return r * 128 + (c ^ (((r >> 1) & 7) << 2));
}

__global__ __launch_bounds__(256) void k_pair(
    const float* __restrict__ hlhr,
    fp W2r, fp b2r, fp W2c, fp b2c, fp W2e, fp b2e,
    float* __restrict__ out) {
    __shared__ __align__(16) float hlT[32 * 128];
    __shared__ __align__(16) float hrT[32 * 128];
    __shared__ __align__(16) float w2a[HID];
    __shared__ __align__(16) float w2b[HID];

    const int h  = blockIdx.z;
    const int i0 = blockIdx.y * 32;
    const int j0 = blockIdx.x * 32;
    const float* hl = hlhr + (size_t)(h * 2 + 0) * (NW * HID) + i0 * HID;
    const float* hr = hlhr + (size_t)(h * 2 + 1) * (NW * HID) + j0 * HID;

    for (int t = threadIdx.x; t < 32 * HID; t += 256) {
        const int r = t / HID, c = t % HID;
        hlT[swzi(r, c)] = hl[t];
        hrT[swzi(r, c)] = hr[t];
    }
    fp W2 = (h == 0) ? W2r : ((h == 1) ? W2c : W2e);
    fp b2 = (h == 0) ? b2r : ((h == 1) ? b2c : b2e);
    if (threadIdx.x < HID) {
        w2a[threadIdx.x] = W2[threadIdx.x * 2 + 0];
        w2b[threadIdx.x] = W2[threadIdx.x * 2 + 1];
    }
    __syncthreads();

    const int tx = threadIdx.x & 15;   // j micro-tile
    const int ty = threadIdx.x >> 4;   // i micro-tile
    float acc[2][2][2] = {};

#pragma unroll
    for (int k = 0; k < HID; k += 4) {
        const float4 a0 = *(const float4*)&hlT[swzi(ty * 2 + 0, k)];
        const float4 a1 = *(const float4*)&hlT[swzi(ty * 2 + 1, k)];
        const float4 r0 = *(const float4*)&hrT[swzi(tx * 2 + 0, k)];
        const float4 r1 = *(const float4*)&hrT[swzi(tx * 2 + 1, k)];
        const float4 wa = *(const float4*)&w2a[k];
        const float4 wb = *(const float4*)&w2b[k];
#define STEP(cmp)                                                              \
        {                                                                      \
            const float h00 = fmaxf(a0.cmp + r0.cmp, 0.f);                     \
            const float h01 = fmaxf(a0.cmp + r1.cmp, 0.f);                     \
            const float h10 = fmaxf(a1.cmp + r0.cmp, 0.f);                     \
            const float h11 = fmaxf(a1.cmp + r1.cmp, 0.f);                     \
            acc[0][0][0] = fmaf(h00, wa.cmp, acc[0][0][0]);                    \
            acc[0][0][1] = fmaf(h00, wb.cmp, acc[0][0][1]);                    \
            acc[0][1][0] = fmaf(h01, wa.cmp, acc[0][1][0]);                    \
            acc[0][1][1] = fmaf(h01, wb.cmp, acc[0][1][1]);                    \
            acc[1][0][0] = fmaf(h10, wa.cmp, acc[1][0][0]);                    \
            acc[1][0][1] = fmaf(h10, wb.cmp, acc[1][0][1]);                    \
            acc[1][1][0] = fmaf(h11, wa.cmp, acc[1][1][0]);                    \
            acc[1][1][1] = fmaf(h11, wb.cmp, acc[1][1][1]);                    \
        }
        STEP(x) STEP(y) STEP(z) STEP(w)
#undef STEP
    }

    const float b20 = b2[0];
    const float b21 = b2[1];
#pragma unroll
    for (int ii = 0; ii < 2; ++ii)
#pragma unroll
        for (int jj = 0; jj < 2; ++jj) {
            const int i = i0 + ty * 2 + ii;
            const int j = j0 + tx * 2 + jj;
            const size_t o = ((size_t)(h * NW + i) * NW + j) * 2;
            float2 v;
            v.x = acc[ii][jj][0] + b20;
            v.y = acc[ii][jj][1] + b21;
            *reinterpret_cast<float2*>(out + o) = v;   // f32 output
        }
}

// ---------------------------------------------------------------------------
extern "C" void kernel_launch(void* const* d_in, const int* in_sizes, int n_in,
                              void* d_out, int out_size, void* d_ws,
                              size_t ws_size, hipStream_t stream) {
    // Size-driven operand mapping: robust to dict-vs-signature ordering (the
    // relative order within each equal-size group is identical under both).
    int i_vv = -1, i_idx = -1, i_nf = -1, i_AW = -1, i_BW = -1;
    int tens[3] = {-1, -1, -1}; int n10 = 0;   // B2_Wo, B2_Wh, D_W
    int w1s[3]  = {-1, -1, -1}; int n20 = 0;   // rows/cols/cells W1
    int w2s[3]  = {-1, -1, -1}; int n200 = 0;  // rows/cols/cells W2
    int b100[8] = {-1, -1, -1, -1, -1, -1, -1, -1}; int nb = 0;
    int b2s[3]  = {-1, -1, -1}; int nb2 = 0;   // rows/cols/cells b2
    for (int i = 0; i < n_in; ++i) {
        switch (in_sizes[i]) {
            case 236544: i_vv = i; break;
            case 3840:   i_idx = i; break;
            case 768:    i_nf = i; break;
            case 30800:  i_AW = i; break;
            case 60000:  i_BW = i; break;
            case 10000:  if (n10 < 3) tens[n10++] = i; break;
            case 20000:  if (n20 < 3) w1s[n20++] = i; break;
            case 200:    if (n200 < 3) w2s[n200++] = i; break;
            case 100:    if (nb < 8) b100[nb++] = i; break;
            case 2:      if (nb2 < 3) b2s[nb2++] = i; break;
            default: break;  // num_words (size 1)
        }
    }
    fp vv          = (fp)d_in[i_vv];
    const int* idx = (const int*)d_in[i_idx];
    const int* nf  = (const int*)d_in[i_nf];
    fp A_W = (fp)d_in[i_AW],      A_b   = (fp)d_in[b100[0]];
    fp B_W = (fp)d_in[i_BW],      B_b   = (fp)d_in[b100[1]];
    fp B2_Wo = (fp)d_in[tens[0]], B2_bo = (fp)d_in[b100[2]];
    fp W1r = (fp)d_in[w1s[0]], b1r = (fp)d_in[b100[5]];
    fp W1c = (fp)d_in[w1s[1]], b1c = (fp)d_in[b100[6]];
    fp W1e = (fp)d_in[w1s[2]], b1e = (fp)d_in[b100[7]];
    fp W2r = (fp)d_in[w2s[0]], b2r = (fp)d_in[b2s[0]];
    fp W2c = (fp)d_in[w2s[1]], b2c = (fp)d_in[b2s[1]];
    fp W2e = (fp)d_in[w2s[2]], b2e = (fp)d_in[b2s[2]];

    float* out = (float*)d_out;   // reference output dtype = float32

    float* ws   = (float*)d_ws;
    float* uu   = ws;                        // 768*100 f32
    float* hlhr = ws + NW * HID;             // 3*2*768*100 f32
    int*   modes = (int*)(ws + NW * HID + 6 * NW * HID);

    k_probe<<<1, 192, 0, stream>>>(nf, idx, modes);
    k_uu<<<NW, 128, 0, stream>>>(vv, A_W, A_b, uu);
    k_fused<<<NW, 128, 0, stream>>>(uu, idx, nf, modes, B_W, B_b, B2_Wo, B2_bo,
                                    W1r, b1r, W1c, b1c, W1e, b1e, hlhr);
    dim3 grid(NW / 32, NW / 32, 3);
    k_pair<<<grid, 256, 0, stream>>>(hlhr, W2r, b2r, W2c, b2c, W2e, b2e, out);
}

// Round 5
// 54.710 us; speedup vs baseline: 1.4114x; 1.4114x over previous
//
#include <hip/hip_runtime.h>
#include <hip/hip_bf16.h>

// Problem constants (reference: N=768, D_IN=308, H=100, iterations=1)
// Inputs f32, output f32 (verified round 4). hh==0 on the single iteration,
// so B_W[500:600], B2_Wh, D_W/b are dead.
#define NW   768
#define HID  100
#define DIN  308
#define RPB  2          // rows per block in k_uu / k_fused

typedef const float* fp;

// ---------------------------------------------------------------------------
// K0: probe integer-tensor storage (verified working round 4).
// modes[0] (nf):  0=int32/word, 1=packed uint8, 2=int64
// modes[1] (idx): 0=int32, 1=int64
// ---------------------------------------------------------------------------
__global__ __launch_bounds__(192) void k_probe(const int* __restrict__ nf,
                                               const int* __restrict__ idx,
                                               int* __restrict__ modes) {
    __shared__ int bigNF, badNF, oddNF, evenNF, oddIX, evenIX;
    if (threadIdx.x == 0) { bigNF = badNF = oddNF = evenNF = oddIX = evenIX = 0; }
    __syncthreads();
    const int t = threadIdx.x;
    const unsigned vn = (unsigned)nf[t];
    if (vn > 1u) atomicOr(&bigNF, 1);
    if (vn & 0xFEFEFEFEu) atomicOr(&badNF, 1);
    if ((t & 1) && vn) atomicOr(&oddNF, 1);
    if (!(t & 1) && vn) atomicOr(&evenNF, 1);
    const unsigned vi = (unsigned)idx[t];
    if ((t & 1) && vi) atomicOr(&oddIX, 1);
    if (!(t & 1) && vi) atomicOr(&evenIX, 1);
    __syncthreads();
    if (t == 0) {
        int m = 0;
        if (!badNF && bigNF) m = 1;
        else if (!oddNF && evenNF) m = 2;
        modes[0] = m;
        modes[1] = (!oddIX && evenIX) ? 1 : 0;
    }
}

// ---------------------------------------------------------------------------
// K1 v2: uu = tanh(vv @ A_W + A_b).  RPB rows/block, 512 thr = 4 k-slices
// (77 each) x 128 cols, LDS partial reduce. Cuts serial load chain 4x.
// ---------------------------------------------------------------------------
__global__ __launch_bounds__(512) void k_uu(fp vv, fp A_W, fp A_b,
                                            float* __restrict__ uu) {
    __shared__ float vs[RPB][DIN];
    __shared__ float part[4][RPB][128];
    const int i0 = blockIdx.x * RPB;
    for (int t = threadIdx.x; t < RPB * DIN; t += 512) {
        const int r = t / DIN, k = t % DIN;
        vs[r][k] = vv[(i0 + r) * DIN + k];
    }
    __syncthreads();
    const int c = threadIdx.x & 127;
    const int s = threadIdx.x >> 7;          // 0..3, k-slice of 77
    float a0 = 0.f, a1 = 0.f;
    if (c < HID) {
        const int k0 = s * 77;
#pragma unroll 11
        for (int k = k0; k < k0 + 77; ++k) {
            const float w = A_W[k * HID + c];
            a0 = fmaf(vs[0][k], w, a0);
            a1 = fmaf(vs[1][k], w, a1);
        }
    }
    part[s][0][c] = a0; part[s][1][c] = a1;
    __syncthreads();
    for (int t = threadIdx.x; t < RPB * HID; t += 512) {
        const int r = t / HID, cc = t % HID;
        float acc = A_b[cc];
#pragma unroll
        for (int s2 = 0; s2 < 4; ++s2) acc += part[s2][r][cc];
        uu[(i0 + r) * HID + cc] = tanhf(acc);
    }
}

// ---------------------------------------------------------------------------
// K2 v2 (fused): gather ww -> bb -> oo -> hl/hr for 3 heads.
// RPB rows/block, 640 thr = 5 k-slices x 128 cols.
//   B-stage : K=500 -> 5 x 100, LDS reduce, tanh
//   oo-stage: K=100 -> 5 x 20,  LDS reduce, tanh
//   W1-stage: 600 outputs (3 heads x hl/hr x 100 cols), K=100 serial
// hlhr layout: [h*2+half][row][100] f32. b1 folded into hl.
// ---------------------------------------------------------------------------
__global__ __launch_bounds__(640) void k_fused(
    const float* __restrict__ uu, const int* __restrict__ indices,
    const int* __restrict__ nf, const int* __restrict__ modes,
    fp B_W, fp B_b, fp B2_Wo, fp B2_bo,
    fp W1r, fp b1r, fp W1c, fp b1c, fp W1e, fp b1e,
    float* __restrict__ hlhr) {
    __shared__ float ww[RPB][5 * HID];
    __shared__ float part[5][RPB][128];
    __shared__ float bbs[RPB][HID];
    __shared__ float oos[RPB][HID];
    const int i0 = blockIdx.x * RPB;
    const int mnf = modes[0], midx = modes[1];

    // gather 5 neighbor rows per block-row (zeroed if not_found)
    for (int t = threadIdx.x; t < RPB * 5 * HID; t += 640) {
        const int r = t / (5 * HID), u = t % (5 * HID);
        const int i = i0 + r;
        const bool notf = (mnf == 1) ? (((const unsigned char*)nf)[i] != 0)
                        : (mnf == 2) ? (nf[2 * i] != 0)
                                     : (nf[i] != 0);
        const int q = u / HID, cc = u % HID;
        int j = midx ? indices[2 * (i * 5 + q)] : indices[i * 5 + q];
        j = (j < 0) ? 0 : ((j >= NW) ? NW - 1 : j);
        ww[r][u] = notf ? 0.f : uu[j * HID + cc];
    }
    __syncthreads();

    const int c = threadIdx.x % 128;
    const int s = threadIdx.x / 128;        // 0..4

    // ---- B-stage: k-slice of 100
    {
        float a0 = 0.f, a1 = 0.f;
        if (c < HID) {
            const int k0 = s * 100;
#pragma unroll 10
            for (int k = k0; k < k0 + 100; ++k) {
                const float w = B_W[k * HID + c];
                a0 = fmaf(ww[0][k], w, a0);
                a1 = fmaf(ww[1][k], w, a1);
            }
        }
        part[s][0][c] = a0; part[s][1][c] = a1;
    }
    __syncthreads();
    for (int t = threadIdx.x; t < RPB * HID; t += 640) {
        const int r = t / HID, cc = t % HID;
        float acc = B_b[cc];
#pragma unroll
        for (int s2 = 0; s2 < 5; ++s2) acc += part[s2][r][cc];
        bbs[r][cc] = tanhf(acc);
    }
    __syncthreads();   // all reads of part done before reuse

    // ---- oo-stage: k-slice of 20
    {
        float a0 = 0.f, a1 = 0.f;
        if (c < HID) {
            const int k0 = s * 20;
#pragma unroll 10
            for (int k = k0; k < k0 + 20; ++k) {
                const float w = B2_Wo[k * HID + c];
                a0 = fmaf(bbs[0][k], w, a0);
                a1 = fmaf(bbs[1][k], w, a1);
            }
        }
        part[s][0][c] = a0; part[s][1][c] = a1;
    }
    __syncthreads();
    for (int t = threadIdx.x; t < RPB * HID; t += 640) {
        const int r = t / HID, cc = t % HID;
        float acc = B2_bo[cc];
#pragma unroll
        for (int s2 = 0; s2 < 5; ++s2) acc += part[s2][r][cc];
        oos[r][cc] = tanhf(acc);
    }
    __syncthreads();

    // ---- W1-stage: 600 outputs, K=100 serial (loads shared across RPB rows)
    const int u = threadIdx.x;
    if (u < 600) {
        const int ho = u / HID;             // 0..5 = h*2+half
        const int cc = u % HID;
        const int h = ho >> 1, half = ho & 1;
        fp W1 = (h == 0) ? W1r : ((h == 1) ? W1c : W1e);
        fp b1 = (h == 0) ? b1r : ((h == 1) ? b1c : b1e);
        const float bias = half ? 0.f : b1[cc];
        float a0 = bias, a1 = bias;
        const float* Wp = W1 + half * HID * HID;
#pragma unroll 10
        for (int k = 0; k < HID; ++k) {
            const float w = Wp[k * HID + cc];
            a0 = fmaf(oos[0][k], w, a0);
            a1 = fmaf(oos[1][k], w, a1);
        }
        hlhr[(size_t)ho * (NW * HID) + (size_t)(i0 + 0) * HID + cc] = a0;
        hlhr[(size_t)ho * (NW * HID) + (size_t)(i0 + 1) * HID + cc] = a1;
    }
}

// ---------------------------------------------------------------------------
// K3: out[h][i][j][:] = relu(hl_i + hr_j) @ W2h + b2h   (f32 output)
// 32x32 pair tile / block (256 thr), 2x2 micro-tile / thread, swizzled LDS.
// ---------------------------------------------------------------------------
__device__ __forceinline__ int swzi(int r, int c) {
    return r * 128 + (c ^ (((r >> 1) & 7) << 2));
}

__global__ __launch_bounds__(256) void k_pair(
    const float* __restrict__ hlhr,
    fp W2r, fp b2r, fp W2c, fp b2c, fp W2e, fp b2e,
    float* __restrict__ out) {
    __shared__ __align__(16) float hlT[32 * 128];
    __shared__ __align__(16) float hrT[32 * 128];
    __shared__ __align__(16) float w2a[HID];
    __shared__ __align__(16) float w2b[HID];

    const int h  = blockIdx.z;
    const int i0 = blockIdx.y * 32;
    const int j0 = blockIdx.x * 32;
    const float* hl = hlhr + (size_t)(h * 2 + 0) * (NW * HID) + i0 * HID;
    const float* hr = hlhr + (size_t)(h * 2 + 1) * (NW * HID) + j0 * HID;

    for (int t = threadIdx.x; t < 32 * HID; t += 256) {
        const int r = t / HID, c = t % HID;
        hlT[swzi(r, c)] = hl[t];
        hrT[swzi(r, c)] = hr[t];
    }
    fp W2 = (h == 0) ? W2r : ((h == 1) ? W2c : W2e);
    fp b2 = (h == 0) ? b2r : ((h == 1) ? b2c : b2e);
    if (threadIdx.x < HID) {
        w2a[threadIdx.x] = W2[threadIdx.x * 2 + 0];
        w2b[threadIdx.x] = W2[threadIdx.x * 2 + 1];
    }
    __syncthreads();

    const int tx = threadIdx.x & 15;
    const int ty = threadIdx.x >> 4;
    float acc[2][2][2] = {};

#pragma unroll
    for (int k = 0; k < HID; k += 4) {
        const float4 a0 = *(const float4*)&hlT[swzi(ty * 2 + 0, k)];
        const float4 a1 = *(const float4*)&hlT[swzi(ty * 2 + 1, k)];
        const float4 r0 = *(const float4*)&hrT[swzi(tx * 2 + 0, k)];
        const float4 r1 = *(const float4*)&hrT[swzi(tx * 2 + 1, k)];
        const float4 wa = *(const float4*)&w2a[k];
        const float4 wb = *(const float4*)&w2b[k];
#define STEP(cmp)                                                              \
        {                                                                      \
            const float h00 = fmaxf(a0.cmp + r0.cmp, 0.f);                     \
            const float h01 = fmaxf(a0.cmp + r1.cmp, 0.f);                     \
            const float h10 = fmaxf(a1.cmp + r0.cmp, 0.f);                     \
            const float h11 = fmaxf(a1.cmp + r1.cmp, 0.f);                     \
            acc[0][0][0] = fmaf(h00, wa.cmp, acc[0][0][0]);                    \
            acc[0][0][1] = fmaf(h00, wb.cmp, acc[0][0][1]);                    \
            acc[0][1][0] = fmaf(h01, wa.cmp, acc[0][1][0]);                    \
            acc[0][1][1] = fmaf(h01, wb.cmp, acc[0][1][1]);                    \
            acc[1][0][0] = fmaf(h10, wa.cmp, acc[1][0][0]);                    \
            acc[1][0][1] = fmaf(h10, wb.cmp, acc[1][0][1]);                    \
            acc[1][1][0] = fmaf(h11, wa.cmp, acc[1][1][0]);                    \
            acc[1][1][1] = fmaf(h11, wb.cmp, acc[1][1][1]);                    \
        }
        STEP(x) STEP(y) STEP(z) STEP(w)
#undef STEP
    }

    const float b20 = b2[0];
    const float b21 = b2[1];
#pragma unroll
    for (int ii = 0; ii < 2; ++ii)
#pragma unroll
        for (int jj = 0; jj < 2; ++jj) {
            const int i = i0 + ty * 2 + ii;
            const int j = j0 + tx * 2 + jj;
            const size_t o = ((size_t)(h * NW + i) * NW + j) * 2;
            float2 v;
            v.x = acc[ii][jj][0] + b20;
            v.y = acc[ii][jj][1] + b21;
            *reinterpret_cast<float2*>(out + o) = v;
        }
}

// ---------------------------------------------------------------------------
extern "C" void kernel_launch(void* const* d_in, const int* in_sizes, int n_in,
                              void* d_out, int out_size, void* d_ws,
                              size_t ws_size, hipStream_t stream) {
    int i_vv = -1, i_idx = -1, i_nf = -1, i_AW = -1, i_BW = -1;
    int tens[3] = {-1, -1, -1}; int n10 = 0;   // B2_Wo, B2_Wh, D_W
    int w1s[3]  = {-1, -1, -1}; int n20 = 0;
    int w2s[3]  = {-1, -1, -1}; int n200 = 0;
    int b100[8] = {-1, -1, -1, -1, -1, -1, -1, -1}; int nb = 0;
    int b2s[3]  = {-1, -1, -1}; int nb2 = 0;
    for (int i = 0; i < n_in; ++i) {
        switch (in_sizes[i]) {
            case 236544: i_vv = i; break;
            case 3840:   i_idx = i; break;
            case 768:    i_nf = i; break;
            case 30800:  i_AW = i; break;
            case 60000:  i_BW = i; break;
            case 10000:  if (n10 < 3) tens[n10++] = i; break;
            case 20000:  if (n20 < 3) w1s[n20++] = i; break;
            case 200:    if (n200 < 3) w2s[n200++] = i; break;
            case 100:    if (nb < 8) b100[nb++] = i; break;
            case 2:      if (nb2 < 3) b2s[nb2++] = i; break;
            default: break;
        }
    }
    fp vv          = (fp)d_in[i_vv];
    const int* idx = (const int*)d_in[i_idx];
    const int* nf  = (const int*)d_in[i_nf];
    fp A_W = (fp)d_in[i_AW],      A_b   = (fp)d_in[b100[0]];
    fp B_W = (fp)d_in[i_BW],      B_b   = (fp)d_in[b100[1]];
    fp B2_Wo = (fp)d_in[tens[0]], B2_bo = (fp)d_in[b100[2]];
    fp W1r = (fp)d_in[w1s[0]], b1r = (fp)d_in[b100[5]];
    fp W1c = (fp)d_in[w1s[1]], b1c = (fp)d_in[b100[6]];
    fp W1e = (fp)d_in[w1s[2]], b1e = (fp)d_in[b100[7]];
    fp W2r = (fp)d_in[w2s[0]], b2r = (fp)d_in[b2s[0]];
    fp W2c = (fp)d_in[w2s[1]], b2c = (fp)d_in[b2s[1]];
    fp W2e = (fp)d_in[w2s[2]], b2e = (fp)d_in[b2s[2]];

    float* out = (float*)d_out;

    float* ws    = (float*)d_ws;
    float* uu    = ws;                       // 768*100 f32
    float* hlhr  = ws + NW * HID;            // 6*768*100 f32
    int*   modes = (int*)(ws + NW * HID + 6 * NW * HID);

    k_probe<<<1, 192, 0, stream>>>(nf, idx, modes);
    k_uu<<<NW / RPB, 512, 0, stream>>>(vv, A_W, A_b, uu);
    k_fused<<<NW / RPB, 640, 0, stream>>>(uu, idx, nf, modes, B_W, B_b,
                                          B2_Wo, B2_bo,
                                          W1r, b1r, W1c, b1c, W1e, b1e, hlhr);
    dim3 grid(NW / 32, NW / 32, 3);
    k_pair<<<grid, 256, 0, stream>>>(hlhr, W2r, b2r, W2c, b2c, W2e, b2e, out);
}